// Round 5
// baseline (413.652 us; speedup 1.0000x reference)
//
#include <hip/hip_runtime.h>
#include <math.h>

// TopK router: logits = x[16384,2048] @ w[64,2048]^T ; softmax; top-2 + renorm
// out (f32 flat): idx[32768] | topk_probs[32768] | probs[16384*64]
//
// v4 (single fused kernel):
//  - block = 256 thr = 2 K-halves x 128 thr; BM=32 tokens; grid 512 (2/CU)
//  - thread tile: 8 tokens x 2 experts; x read DIRECT from global (each
//    float4 broadcast to 32 lanes, zero reuse -> no LDS), ping-pong
//    register prefetch xa/xb one kg ahead
//  - w: global->reg (issued at chunk top, T14) -> swizzled ds_write ->
//    double-buffered LDS; read as 2x ds_read_b128/kg with quad XOR
//    swizzle q = kg ^ ((row>>1)&7)  (spans all 8 bank groups for the
//    stride-2 expert rows of a fragment read)
//  - halves combine partial logits in LDS (aliased over w buffers), then
//    per-wave shuffle top-2/softmax epilogue (verified in rounds 2-3)

#define TOK 16384
#define DD  2048
#define EE  64
#define BM  32
#define BK  64
#define KHALF (DD / 2)        // 1024
#define NCH   (KHALF / BK)    // 16

#define OUT_TP    (TOK * 2)
#define OUT_PROBS (TOK * 4)

__global__ __launch_bounds__(256, 2)
void router_v4(const float* __restrict__ x, const float* __restrict__ w,
               float* __restrict__ out) {
    // ws[half][buf][row=expert][quad][4]; quad q of row r holds k-quad (q ^ ((r>>1)&7))
    __shared__ __align__(16) float ws[2][2][EE][16][4];   // 64 KiB exactly

    const int tid  = threadIdx.x;
    const int half = tid >> 7;          // K-half
    const int ht   = tid & 127;
    const int tx   = ht & 31;           // expert pair: rows 2tx, 2tx+1
    const int ty   = ht >> 5;           // token group (8 tokens)
    const int g0   = blockIdx.x * BM;
    const int k0   = half * KHALF;

    // --- w staging map: row sr, 128B half-row qh ---
    const int sr = ht >> 1;             // 0..63
    const int qh = ht & 1;              // 0..1
    const int sf = (sr >> 1) & 7;       // swizzle value for row sr
    const float* wsrc = w + (size_t)sr * DD + k0 + qh * 32;

    // --- x row pointers (8 tokens), half-local k base ---
    const float* xrow[8];
#pragma unroll
    for (int i = 0; i < 8; ++i)
        xrow[i] = x + (size_t)(g0 + ty * 8 + i) * DD + k0;

    float acc[8][2];
#pragma unroll
    for (int i = 0; i < 8; ++i) { acc[i][0] = 0.f; acc[i][1] = 0.f; }

    // ---- prologue: stage w chunk 0; preload x kg0, kg1 ----
    float4 wreg[8];
#pragma unroll
    for (int s = 0; s < 8; ++s)
        wreg[s] = *(const float4*)(wsrc + s * 4);
#pragma unroll
    for (int s = 0; s < 8; ++s)
        *(float4*)&ws[half][0][sr][qh * 8 + (s ^ sf)][0] = wreg[s];

    float4 xa[8], xb[8];
#pragma unroll
    for (int i = 0; i < 8; ++i) xa[i] = *(const float4*)(xrow[i] + 0);
#pragma unroll
    for (int i = 0; i < 8; ++i) xb[i] = *(const float4*)(xrow[i] + 4);

    __syncthreads();

    const int rA  = 2 * tx;
    const int frd = tx & 7;             // read-side swizzle (same for both rows)

#define FMA16(XV)                                              \
    _Pragma("unroll")                                          \
    for (int i = 0; i < 8; ++i) {                              \
        acc[i][0] = fmaf(XV[i].x, w0.x, acc[i][0]);            \
        acc[i][0] = fmaf(XV[i].y, w0.y, acc[i][0]);            \
        acc[i][0] = fmaf(XV[i].z, w0.z, acc[i][0]);            \
        acc[i][0] = fmaf(XV[i].w, w0.w, acc[i][0]);            \
        acc[i][1] = fmaf(XV[i].x, w1.x, acc[i][1]);            \
        acc[i][1] = fmaf(XV[i].y, w1.y, acc[i][1]);            \
        acc[i][1] = fmaf(XV[i].z, w1.z, acc[i][1]);            \
        acc[i][1] = fmaf(XV[i].w, w1.w, acc[i][1]);            \
    }

#pragma unroll 1
    for (int c = 0; c < NCH; ++c) {
        // T14: issue next w chunk's global loads early
        if (c + 1 < NCH) {
#pragma unroll
            for (int s = 0; s < 8; ++s)
                wreg[s] = *(const float4*)(wsrc + (c + 1) * BK + s * 4);
        }
        const int buf = c & 1;
        const int kc  = c * BK;         // half-local k of chunk start

#pragma unroll 1
        for (int kg = 0; kg < 16; kg += 2) {
            // step A: kg (consume xa, then reload xa <- kg+2)
            {
                float4 w0 = *(const float4*)&ws[half][buf][rA + 0][kg ^ frd][0];
                float4 w1 = *(const float4*)&ws[half][buf][rA + 1][kg ^ frd][0];
                FMA16(xa)
                const int nk = kc + kg * 4 + 8;
                if (nk < KHALF) {
#pragma unroll
                    for (int i = 0; i < 8; ++i)
                        xa[i] = *(const float4*)(xrow[i] + nk);
                }
            }
            // step B: kg+1 (consume xb, then reload xb <- kg+3)
            {
                float4 w0 = *(const float4*)&ws[half][buf][rA + 0][(kg + 1) ^ frd][0];
                float4 w1 = *(const float4*)&ws[half][buf][rA + 1][(kg + 1) ^ frd][0];
                FMA16(xb)
                const int nk = kc + kg * 4 + 12;
                if (nk < KHALF) {
#pragma unroll
                    for (int i = 0; i < 8; ++i)
                        xb[i] = *(const float4*)(xrow[i] + nk);
                }
            }
        }

        // late swizzled ds_write into the other buffer, one barrier per chunk
        if (c + 1 < NCH) {
#pragma unroll
            for (int s = 0; s < 8; ++s)
                *(float4*)&ws[half][buf ^ 1][sr][qh * 8 + (s ^ sf)][0] = wreg[s];
        }
        __syncthreads();
    }

    // ---- combine halves: partial logits in LDS (alias over ws) ----
    float* lg = (float*)&ws[0][0][0][0][0];   // [32][65]
    if (half == 0) {
#pragma unroll
        for (int i = 0; i < 8; ++i)
#pragma unroll
            for (int j = 0; j < 2; ++j)
                lg[(ty * 8 + i) * 65 + rA + j] = acc[i][j];
    }
    __syncthreads();
    if (half == 1) {
#pragma unroll
        for (int i = 0; i < 8; ++i)
#pragma unroll
            for (int j = 0; j < 2; ++j)
                lg[(ty * 8 + i) * 65 + rA + j] += acc[i][j];
    }
    __syncthreads();

    // ---- epilogue: 4 waves x 8 tokens, lane = expert ----
    const int lane = tid & 63;
    const int wid  = tid >> 6;
#pragma unroll
    for (int t = 0; t < 8; ++t) {
        const int  tok = wid * 8 + t;
        const float v  = lg[tok * 65 + lane];

        float m1 = v; int i1 = lane;
#pragma unroll
        for (int s = 32; s > 0; s >>= 1) {
            float ov = __shfl_xor(m1, s, 64);
            int   oi = __shfl_xor(i1, s, 64);
            if (ov > m1 || (ov == m1 && oi < i1)) { m1 = ov; i1 = oi; }
        }
        float m2 = (lane == i1) ? -INFINITY : v; int i2 = lane;
#pragma unroll
        for (int s = 32; s > 0; s >>= 1) {
            float ov = __shfl_xor(m2, s, 64);
            int   oi = __shfl_xor(i2, s, 64);
            if (ov > m2 || (ov == m2 && oi < i2)) { m2 = ov; i2 = oi; }
        }

        float e = __expf(v - m1);
        float ssum = e;
#pragma unroll
        for (int s = 32; s > 0; s >>= 1) ssum += __shfl_xor(ssum, s, 64);
        const float inv = 1.f / ssum;

        const size_t g = (size_t)(g0 + tok);
        out[OUT_PROBS + g * EE + lane] = e * inv;

        if (lane == 0) {
            float p1 = inv;
            float p2 = __expf(m2 - m1) * inv;
            float den = p1 + p2 + 1e-9f;
            out[g * 2 + 0] = (float)i1;
            out[g * 2 + 1] = (float)i2;
            out[OUT_TP + g * 2 + 0] = p1 / den;
            out[OUT_TP + g * 2 + 1] = p2 / den;
        }
    }
}

extern "C" void kernel_launch(void* const* d_in, const int* in_sizes, int n_in,
                              void* d_out, int out_size, void* d_ws, size_t ws_size,
                              hipStream_t stream) {
    const float* x = (const float*)d_in[0];   // [4,4096,2048] f32
    const float* w = (const float*)d_in[1];   // [64,2048] f32
    router_v4<<<TOK / BM, 256, 0, stream>>>(x, w, (float*)d_out);
}

// Round 6
// 370.196 us; speedup vs baseline: 1.1174x; 1.1174x over previous
//
#include <hip/hip_runtime.h>
#include <math.h>

// TopK router: logits = x[16384,2048] @ w[64,2048]^T ; softmax; top-2 + renorm
// out (f32 flat): idx[32768] | topk_probs[32768] | probs[16384*64]
//
// v5: single fused kernel, 512 threads = 2 K-halves x 256 thr, BM=32 tokens,
// grid 512 (2 blocks/CU = 16 waves/CU). Thread tile 4 tokens x 2 experts
// (c, c+32) -> ~80 VGPR, spill-proof. w staged via global_load_lds (zero
// VGPR), double-buffered, e-major granules with kq-XOR swizzle
// pos = kg ^ (e&7) (read lanes span all 8 bank groups). x read direct from
// global (broadcast-coalesced across 32 lanes), 2-slot ping-pong, reload
// index wrapped with & (KHALF-1) so the inner loop is branch-free.
// Halves combine logits in LDS (aliased over w buffers), then the
// round-2/3-verified shuffle top-2/softmax epilogue.

#define TOK 16384
#define DD  2048
#define EE  64
#define BM  32
#define BK  64
#define KHALF (DD / 2)      // 1024
#define NCH   (KHALF / BK)  // 16

#define OUT_TP    (TOK * 2)
#define OUT_PROBS (TOK * 4)

typedef unsigned int u32;
typedef __attribute__((address_space(3))) u32 lds_u32;
typedef const __attribute__((address_space(1))) u32 glb_u32;

static __device__ __forceinline__ void gload16(const float* g, void* l) {
    __builtin_amdgcn_global_load_lds((glb_u32*)(const void*)g,
                                     (lds_u32*)l, 16, 0, 0);
}

__global__ __launch_bounds__(512, 4)
void router_v5(const float* __restrict__ x, const float* __restrict__ w,
               float* __restrict__ out) {
    // wt[half][buf][granule]: granule (e, pos) holds w[e][ck + 4*(pos^(e&7))..+3]
    __shared__ __align__(16) float4 wt[2][2][EE * 16];   // 64 KiB

    const int tid  = threadIdx.x;
    const int half = tid >> 8;          // K-half
    const int ht   = tid & 255;
    const int c    = ht & 31;           // expert col: experts c, c+32
    const int r    = ht >> 5;           // token row group (4 tokens)
    const int g0   = blockIdx.x * BM;
    const int k0   = half * KHALF;
    const int sw   = c & 7;             // read-side swizzle (same for c, c+32)

    // --- w staging map: 4 granules/thread/chunk, linear dest, swizzled src ---
    const float* wsrc[4];
    int wdst[4];
#pragma unroll
    for (int it = 0; it < 4; ++it) {
        const int p  = it * 256 + ht;           // dest granule
        const int e  = p >> 4;
        const int kq = (p & 15) ^ (e & 7);      // source k-quad (involution)
        wsrc[it] = w + (size_t)e * DD + k0 + kq * 4;
        wdst[it] = p;
    }

    // --- x row pointers (4 tokens), half-local k base ---
    const float* xr[4];
#pragma unroll
    for (int i = 0; i < 4; ++i)
        xr[i] = x + (size_t)(g0 + r * 4 + i) * DD + k0;

    float acc[4][2] = {{0.f}};

    // ---- prologue: stage w chunk 0; preload x kg0, kg1 ----
#pragma unroll
    for (int it = 0; it < 4; ++it)
        gload16(wsrc[it], &wt[half][0][wdst[it]]);

    float4 xa[4], xb[4];
#pragma unroll
    for (int i = 0; i < 4; ++i) xa[i] = *(const float4*)(xr[i] + 0);
#pragma unroll
    for (int i = 0; i < 4; ++i) xb[i] = *(const float4*)(xr[i] + 4);

    __syncthreads();

#define FMA8(XS)                                           \
    _Pragma("unroll")                                      \
    for (int i = 0; i < 4; ++i) {                          \
        acc[i][0] = fmaf(XS[i].x, w0.x, acc[i][0]);        \
        acc[i][0] = fmaf(XS[i].y, w0.y, acc[i][0]);        \
        acc[i][0] = fmaf(XS[i].z, w0.z, acc[i][0]);        \
        acc[i][0] = fmaf(XS[i].w, w0.w, acc[i][0]);        \
        acc[i][1] = fmaf(XS[i].x, w1.x, acc[i][1]);        \
        acc[i][1] = fmaf(XS[i].y, w1.y, acc[i][1]);        \
        acc[i][1] = fmaf(XS[i].z, w1.z, acc[i][1]);        \
        acc[i][1] = fmaf(XS[i].w, w1.w, acc[i][1]);        \
    }

#pragma unroll 1
    for (int cc = 0; cc < NCH; ++cc) {
        const int buf = cc & 1;
        // stage next chunk into the other buffer (lands during compute)
        if (cc + 1 < NCH) {
#pragma unroll
            for (int it = 0; it < 4; ++it)
                gload16(wsrc[it] + (cc + 1) * BK, &wt[half][buf ^ 1][wdst[it]]);
        }

        const float4* wb = &wt[half][buf][0];
#pragma unroll
        for (int kg = 0; kg < 16; ++kg) {
            const float4 w0 = wb[(c << 4) + (kg ^ sw)];
            const float4 w1 = wb[((c + 32) << 4) + (kg ^ sw)];
            if ((kg & 1) == 0) {
                FMA8(xa)
                const int nk = (cc * BK + kg * 4 + 8) & (KHALF - 1);
#pragma unroll
                for (int i = 0; i < 4; ++i)
                    xa[i] = *(const float4*)(xr[i] + nk);
            } else {
                FMA8(xb)
                const int nk = (cc * BK + kg * 4 + 8) & (KHALF - 1);
#pragma unroll
                for (int i = 0; i < 4; ++i)
                    xb[i] = *(const float4*)(xr[i] + nk);
            }
        }
        __syncthreads();
    }

    // ---- combine halves: logits in LDS (alias over wt[0][0], 8.3 KB) ----
    float* lg = (float*)&wt[0][0][0];   // [32][65]
    if (half == 0) {
#pragma unroll
        for (int i = 0; i < 4; ++i)
#pragma unroll
            for (int j = 0; j < 2; ++j)
                lg[(r * 4 + i) * 65 + c + 32 * j] = acc[i][j];
    }
    __syncthreads();
    if (half == 1) {
#pragma unroll
        for (int i = 0; i < 4; ++i)
#pragma unroll
            for (int j = 0; j < 2; ++j)
                lg[(r * 4 + i) * 65 + c + 32 * j] += acc[i][j];
    }
    __syncthreads();

    // ---- epilogue: 8 waves x 4 tokens, lane = expert ----
    const int lane = tid & 63;
    const int wid  = tid >> 6;          // 0..7
#pragma unroll
    for (int t = 0; t < 4; ++t) {
        const int  tok = wid * 4 + t;
        const float v  = lg[tok * 65 + lane];

        float m1 = v; int i1 = lane;
#pragma unroll
        for (int s = 32; s > 0; s >>= 1) {
            float ov = __shfl_xor(m1, s, 64);
            int   oi = __shfl_xor(i1, s, 64);
            if (ov > m1 || (ov == m1 && oi < i1)) { m1 = ov; i1 = oi; }
        }
        float m2 = (lane == i1) ? -INFINITY : v; int i2 = lane;
#pragma unroll
        for (int s = 32; s > 0; s >>= 1) {
            float ov = __shfl_xor(m2, s, 64);
            int   oi = __shfl_xor(i2, s, 64);
            if (ov > m2 || (ov == m2 && oi < i2)) { m2 = ov; i2 = oi; }
        }

        float e = __expf(v - m1);
        float ssum = e;
#pragma unroll
        for (int s = 32; s > 0; s >>= 1) ssum += __shfl_xor(ssum, s, 64);
        const float inv = 1.f / ssum;

        const size_t g = (size_t)(g0 + tok);
        out[OUT_PROBS + g * EE + lane] = e * inv;

        if (lane == 0) {
            float p1 = inv;
            float p2 = __expf(m2 - m1) * inv;
            float den = p1 + p2 + 1e-9f;
            out[g * 2 + 0] = (float)i1;
            out[g * 2 + 1] = (float)i2;
            out[OUT_TP + g * 2 + 0] = p1 / den;
            out[OUT_TP + g * 2 + 1] = p2 / den;
        }
    }
}

extern "C" void kernel_launch(void* const* d_in, const int* in_sizes, int n_in,
                              void* d_out, int out_size, void* d_ws, size_t ws_size,
                              hipStream_t stream) {
    const float* x = (const float*)d_in[0];   // [4,4096,2048] f32
    const float* w = (const float*)d_in[1];   // [64,2048] f32
    router_v5<<<TOK / BM, 512, 0, stream>>>(x, w, (float*)d_out);
}